// Round 2
// baseline (558.053 us; speedup 1.0000x reference)
//
#include <hip/hip_runtime.h>

#define N_NODES 100000
#define N_EDGES 1600000
#define D 64
#define NB 782                 // ceil(100000/128) dst-buckets of 128 nodes
#define CAP 3072               // slab slots per bucket (mean 2048, sigma~45)
#define EPB 8192               // edges per partition block
#define NPART ((N_EDGES + EPB - 1) / EPB)   // 196
#define RSH 14                 // src-range shift: range = src>>14 in 0..6

typedef unsigned short ushort_t;
typedef unsigned int uint_t;

// ---------- K1: repack feat -> bf16 (RNE) + init gcur ----------
__device__ __forceinline__ ushort_t f2bf(float f) {
    uint_t u = __float_as_uint(f);
    u += 0x7FFF + ((u >> 16) & 1);          // round-nearest-even
    return (ushort_t)(u >> 16);
}

__global__ __launch_bounds__(256) void repack_init(const float* __restrict__ feat,
                                                   ushort_t* __restrict__ featb,
                                                   int* __restrict__ gcur) {
    const int tid = blockIdx.x * 256 + threadIdx.x;
    if (tid < NB) gcur[tid] = tid * CAP;
    const int base = tid * 16;              // 16 floats per thread
    if (base >= N_NODES * D) return;
    const float4* f4 = (const float4*)(feat + base);
    ushort4* o4 = (ushort4*)(featb + base);
#pragma unroll
    for (int j = 0; j < 4; ++j) {
        const float4 v = f4[j];
        o4[j] = make_ushort4(f2bf(v.x), f2bf(v.y), f2bf(v.z), f2bf(v.w));
    }
}

// ---------- K2: partition edges into per-bucket slabs ----------
__global__ __launch_bounds__(1024) void partition(const int* __restrict__ esrc,
                                                  const int* __restrict__ edst,
                                                  int* __restrict__ gcur,
                                                  int* __restrict__ slab) {
    __shared__ int stage[EPB];              // 32 KB: packed, sorted by bucket
    __shared__ ushort_t bkt16[EPB];         // 16 KB: bucket of sorted pos
    __shared__ int cnt[NB];
    __shared__ int cur[NB];
    __shared__ int gb[NB];
    __shared__ int s[1024];
    const int t = threadIdx.x;
    const int base = blockIdx.x * EPB;
    const int n = min(EPB, N_EDGES - base);

    if (t < NB) cnt[t] = 0;
    __syncthreads();
    for (int i = t; i < n; i += 1024)
        atomicAdd(&cnt[edst[base + i] >> 7], 1);
    __syncthreads();
    const int v = (t < NB) ? cnt[t] : 0;
    s[t] = v;
    __syncthreads();
    for (int off = 1; off < 1024; off <<= 1) {
        const int x = (t >= off) ? s[t - off] : 0;
        __syncthreads();
        s[t] += x;
        __syncthreads();
    }
    if (t < NB) {
        const int excl = s[t] - v;          // exclusive prefix
        cur[t] = excl;
        gb[t] = (v ? atomicAdd(&gcur[t], v) : 0) - excl;
    }
    __syncthreads();
    for (int i = t; i < n; i += 1024) {     // coalesced re-read (L2-hot)
        const int d = edst[base + i];
        const int bkt = d >> 7;
        const int pos = atomicAdd(&cur[bkt], 1);
        stage[pos] = ((d & 127) << 17) | esrc[base + i];
        bkt16[pos] = (ushort_t)bkt;
    }
    __syncthreads();
    for (int i = t; i < n; i += 1024) {     // coalesced segment writes
        const int bkt = bkt16[i];
        const int gp = gb[bkt] + i;
        if (gp < (bkt + 1) * CAP)           // overflow guard (never expected)
            slab[gp] = stage[i];
    }
}

// ---------- 8-lane all-reduce on the VALU pipe (DPP, no DS ops) ----------
template<int CTRL>
__device__ __forceinline__ float fadd_dpp(float x) {
    const int r = __builtin_amdgcn_update_dpp(0, __float_as_int(x), CTRL, 0xF, 0xF, true);
    return x + __int_as_float(r);
}
__device__ __forceinline__ float red8(float p) {
    p = fadd_dpp<0xB1>(p);    // quad_perm [1,0,3,2]  : xor 1
    p = fadd_dpp<0x4E>(p);    // quad_perm [2,3,0,1]  : xor 2
    p = fadd_dpp<0x141>(p);   // row_half_mirror      : xor within 8
    return p;
}

// cvt 8 bf16 (uint4) -> g[8] fp32, and dot vs h[8]
__device__ __forceinline__ float cvt_dot(const uint4 u, const float* __restrict__ h,
                                         float* __restrict__ g) {
    g[0] = __uint_as_float(u.x << 16); g[1] = __uint_as_float(u.x & 0xFFFF0000u);
    g[2] = __uint_as_float(u.y << 16); g[3] = __uint_as_float(u.y & 0xFFFF0000u);
    g[4] = __uint_as_float(u.z << 16); g[5] = __uint_as_float(u.z & 0xFFFF0000u);
    g[6] = __uint_as_float(u.w << 16); g[7] = __uint_as_float(u.w & 0xFFFF0000u);
    float p = 0.f;
#pragma unroll
    for (int k = 0; k < 8; ++k) p += g[k] * h[k];
    return p;
}

// ---------- K3: fused SDDMM + SpMM + Linear ----------
// One 128-node bucket per block (round-0 structure, no degree perm).
// GEMM fused per-HALF through hN[64][68] which aliases ONLY dead phase-A
// LDS (seA/cnt/cur; seB+rowoff stay live at non-overlapping offsets).
// Total LDS stays 35840 B -> 4 blocks/CU, same as the 49.5us round-0 kernel.
// No accumulator is held across an edge loop (spill-free); only acc1[8]
// (8 regs) is live across the small scalar-accumulator GEMM-half-1.
#define SMEM_BYTES 35840
#define OFF_SEA    12288        // seB @0 (live long), seA @12288 (dead early)
#define OFF_CNT    24576
#define OFF_CUR    28672
#define OFF_S      32768
#define OFF_ROW    34816        // 129 ints, ends 35332
#define OFF_HN     12288        // float[64][68] = 17408 B, ends 29696

#define EDGE_ROUND(ACC, LN)                                                    \
    if ((LN) < nb_nodes) {                                                     \
        float h[8];                                                            \
        {                                                                      \
            const int nidx = nbase + (LN);                                     \
            const float4 ha = feat4[nidx * 16 + 2 * l];                        \
            const float4 hb = feat4[nidx * 16 + 2 * l + 1];                    \
            h[0] = ha.x; h[1] = ha.y; h[2] = ha.z; h[3] = ha.w;                \
            h[4] = hb.x; h[5] = hb.y; h[6] = hb.z; h[7] = hb.w;                \
        }                                                                      \
        int e = rowoff[(LN)];                                                  \
        const int e1 = rowoff[(LN) + 1];                                       \
        for (; e + 3 < e1; e += 4) {                                           \
            const int s0 = seB[e], s1 = seB[e + 1];                            \
            const int s2 = seB[e + 2], s3 = seB[e + 3];                        \
            const uint4 u0 = featb4[s0 * 8 + l];                               \
            const uint4 u1 = featb4[s1 * 8 + l];                               \
            const uint4 u2 = featb4[s2 * 8 + l];                               \
            const uint4 u3 = featb4[s3 * 8 + l];                               \
            float g0[8], g1[8], g2[8], g3[8];                                  \
            float p0 = cvt_dot(u0, h, g0);                                     \
            float p1 = cvt_dot(u1, h, g1);                                     \
            float p2 = cvt_dot(u2, h, g2);                                     \
            float p3 = cvt_dot(u3, h, g3);                                     \
            p0 = red8(p0); p1 = red8(p1); p2 = red8(p2); p3 = red8(p3);        \
            _Pragma("unroll")                                                  \
            for (int k = 0; k < 8; ++k)                                        \
                ACC[k] += g0[k] * p0 + g1[k] * p1 + g2[k] * p2 + g3[k] * p3;   \
        }                                                                      \
        for (; e < e1; ++e) {                                                  \
            const uint4 u0 = featb4[seB[e] * 8 + l];                           \
            float g0[8];                                                       \
            float p0 = red8(cvt_dot(u0, h, g0));                               \
            _Pragma("unroll")                                                  \
            for (int k = 0; k < 8; ++k) ACC[k] += g0[k] * p0;                  \
        }                                                                      \
    }

// per-half 64x64 GEMM: out[row, c] = sum_i hN[row][i] * W[c][i]
// thread: 2 rows (r0, r0+1) x 4 cols (c4..c4+3); scalar accs, float4 loads.
// hN reads broadcast across the 16 lanes sharing (t>>4); W is L1-resident.
#define GEMM_HALF(HBASE)                                                       \
    {                                                                          \
        const int r0 = (t >> 4) * 2;                                           \
        const int c4 = (t & 15) * 4;                                           \
        float a00 = 0.f, a01 = 0.f, a02 = 0.f, a03 = 0.f;                      \
        float a10 = 0.f, a11 = 0.f, a12 = 0.f, a13 = 0.f;                      \
        for (int i4 = 0; i4 < 16; ++i4) {                                      \
            const float4 x0 = *(const float4*)&hN[r0][i4 * 4];                 \
            const float4 x1 = *(const float4*)&hN[r0 + 1][i4 * 4];             \
            const float4 w0 = W4[(c4 + 0) * 16 + i4];                          \
            const float4 w1 = W4[(c4 + 1) * 16 + i4];                          \
            const float4 w2 = W4[(c4 + 2) * 16 + i4];                          \
            const float4 w3 = W4[(c4 + 3) * 16 + i4];                          \
            a00 += x0.x * w0.x + x0.y * w0.y + x0.z * w0.z + x0.w * w0.w;      \
            a01 += x0.x * w1.x + x0.y * w1.y + x0.z * w1.z + x0.w * w1.w;      \
            a02 += x0.x * w2.x + x0.y * w2.y + x0.z * w2.z + x0.w * w2.w;      \
            a03 += x0.x * w3.x + x0.y * w3.y + x0.z * w3.z + x0.w * w3.w;      \
            a10 += x1.x * w0.x + x1.y * w0.y + x1.z * w0.z + x1.w * w0.w;      \
            a11 += x1.x * w1.x + x1.y * w1.y + x1.z * w1.z + x1.w * w1.w;      \
            a12 += x1.x * w2.x + x1.y * w2.y + x1.z * w2.z + x1.w * w2.w;      \
            a13 += x1.x * w3.x + x1.y * w3.y + x1.z * w3.z + x1.w * w3.w;      \
        }                                                                      \
        const int row = (HBASE) + r0;                                          \
        if (row < nb_nodes)                                                    \
            out4[(long)(nbase + row) * 16 + (t & 15)] =                        \
                make_float4(a00, a01, a02, a03);                               \
        if (row + 1 < nb_nodes)                                                \
            out4[(long)(nbase + row + 1) * 16 + (t & 15)] =                    \
                make_float4(a10, a11, a12, a13);                               \
    }

__global__ __launch_bounds__(512) void fused_spmm_gemm(
        const float4* __restrict__ feat4,
        const uint4* __restrict__ featb4,
        const int* __restrict__ slab,
        const int* __restrict__ gcur,
        const float* __restrict__ W,
        float4* __restrict__ out4) {
    __shared__ __align__(16) char smem[SMEM_BYTES];
    int* seB    = (int*)(smem);                      // live through edge loops
    int* seA    = (int*)(smem + OFF_SEA);            // dead after scatter
    int* cnt    = (int*)(smem + OFF_CNT);            // dead after v0/v1 read
    int* cur    = (int*)(smem + OFF_CUR);            // dead after scatter
    int* s      = (int*)(smem + OFF_S);              // dead after prefix sum
    int* rowoff = (int*)(smem + OFF_ROW);            // live through edge loops
    float (*hN)[68] = (float(*)[68])(smem + OFF_HN); // aliases seA/cnt/cur

    const int t = threadIdx.x;
    const int b = blockIdx.x;
    const int nbase = b << 7;
    const int nb_nodes = min(128, N_NODES - nbase);
    const int sbase = b * CAP;
    const int ne = min(gcur[b] - sbase, CAP);
    const float4* W4 = (const float4*)W;

    // ---- phase A: counting sort by (local_dst, src_range) ----
    for (int i = t; i < ne; i += 512) seA[i] = slab[sbase + i];
    cnt[t] = 0; cnt[t + 512] = 0;
    __syncthreads();
    for (int i = t; i < ne; i += 512) {
        const int pk = seA[i];
        atomicAdd(&cnt[((pk >> 17) << 3) | ((pk & 0x1FFFF) >> RSH)], 1);
    }
    __syncthreads();
    const int v0 = cnt[2 * t], v1 = cnt[2 * t + 1];
    const int sum = v0 + v1;
    s[t] = sum;
    __syncthreads();
    for (int off = 1; off < 512; off <<= 1) {
        const int x = (t >= off) ? s[t - off] : 0;
        __syncthreads();
        s[t] += x;
        __syncthreads();
    }
    const int excl = s[t] - sum;
    cur[2 * t] = excl;
    cur[2 * t + 1] = excl + v0;
    __syncthreads();
    if (t < 128) rowoff[t] = cur[t << 3];
    if (t == 0) rowoff[128] = ne;
    __syncthreads();
    for (int i = t; i < ne; i += 512) {
        const int pk = seA[i];
        const int key = ((pk >> 17) << 3) | ((pk & 0x1FFFF) >> RSH);
        const int pos = atomicAdd(&cur[key], 1);
        seB[pos] = pk & 0x1FFFF;
    }
    __syncthreads();                        // seA/cnt/cur/s dead from here

    // ---- phase B: edge loops, GEMM fused per half ----
    const int slot = t >> 3;                // 64 node-slots per block
    const int l = t & 7;                    // lane owns dims 8l..8l+7
    float acc0[8], acc1[8];
#pragma unroll
    for (int k = 0; k < 8; ++k) { acc0[k] = 0.f; acc1[k] = 0.f; }

    EDGE_ROUND(acc0, slot)                  // half 1: nodes 0..63
    *(float4*)&hN[slot][8 * l]     = make_float4(acc0[0], acc0[1], acc0[2], acc0[3]);
    *(float4*)&hN[slot][8 * l + 4] = make_float4(acc0[4], acc0[5], acc0[6], acc0[7]);

    EDGE_ROUND(acc1, slot + 64)             // half 2: nodes 64..127

    __syncthreads();                        // hN(half1) complete
    GEMM_HALF(0)
    __syncthreads();                        // GEMM1 reads done
    *(float4*)&hN[slot][8 * l]     = make_float4(acc1[0], acc1[1], acc1[2], acc1[3]);
    *(float4*)&hN[slot][8 * l + 4] = make_float4(acc1[4], acc1[5], acc1[6], acc1[7]);
    __syncthreads();                        // hN(half2) complete
    GEMM_HALF(64)
}

extern "C" void kernel_launch(void* const* d_in, const int* in_sizes, int n_in,
                              void* d_out, int out_size, void* d_ws, size_t ws_size,
                              hipStream_t stream) {
    const float* feat = (const float*)d_in[0];
    const int*   esrc = (const int*)d_in[1];
    const int*   edst = (const int*)d_in[2];
    const float* W    = (const float*)d_in[3];
    float* out = (float*)d_out;

    char* ws = (char*)d_ws;
    ushort_t* featb = (ushort_t*)(ws);                       // 12.8 MB
    int* slab = (int*)(ws + 12800000);                       // NB*CAP*4 = 9.61 MB
    int* gcur = (int*)(ws + 12800000 + (size_t)NB * CAP * 4);// 3.1 KB

    repack_init<<<(N_NODES * D / 16 + 255) / 256, 256, 0, stream>>>(feat, featb, gcur);
    partition<<<NPART, 1024, 0, stream>>>(esrc, edst, gcur, slab);
    fused_spmm_gemm<<<NB, 512, 0, stream>>>((const float4*)feat, (const uint4*)featb,
                                            slab, gcur, W, (float4*)out);
}

// Round 3
// 173.554 us; speedup vs baseline: 3.2154x; 3.2154x over previous
//
#include <hip/hip_runtime.h>

#define N_NODES 100000
#define N_EDGES 1600000
#define D 64
#define NB 782                 // ceil(100000/128) dst-buckets of 128 nodes
#define CAP 3072               // slab slots per bucket (mean 2048, sigma~45)
#define EPB 8192               // edges per partition block
#define NPART ((N_EDGES + EPB - 1) / EPB)   // 196
#define RSH 14                 // src-range shift: range = src>>14 in 0..6

typedef unsigned short ushort_t;
typedef unsigned int uint_t;

// ---------- K1: repack feat -> bf16 (RNE) + init gcur ----------
__device__ __forceinline__ ushort_t f2bf(float f) {
    uint_t u = __float_as_uint(f);
    u += 0x7FFF + ((u >> 16) & 1);          // round-nearest-even
    return (ushort_t)(u >> 16);
}

__global__ __launch_bounds__(256) void repack_init(const float* __restrict__ feat,
                                                   ushort_t* __restrict__ featb,
                                                   int* __restrict__ gcur) {
    const int tid = blockIdx.x * 256 + threadIdx.x;
    if (tid < NB) gcur[tid] = tid * CAP;
    const int base = tid * 16;              // 16 floats per thread
    if (base >= N_NODES * D) return;
    const float4* f4 = (const float4*)(feat + base);
    ushort4* o4 = (ushort4*)(featb + base);
#pragma unroll
    for (int j = 0; j < 4; ++j) {
        const float4 v = f4[j];
        o4[j] = make_ushort4(f2bf(v.x), f2bf(v.y), f2bf(v.z), f2bf(v.w));
    }
}

// ---------- K2: partition edges into per-bucket slabs ----------
__global__ __launch_bounds__(1024) void partition(const int* __restrict__ esrc,
                                                  const int* __restrict__ edst,
                                                  int* __restrict__ gcur,
                                                  int* __restrict__ slab) {
    __shared__ int stage[EPB];              // 32 KB: packed, sorted by bucket
    __shared__ ushort_t bkt16[EPB];         // 16 KB: bucket of sorted pos
    __shared__ int cnt[NB];
    __shared__ int cur[NB];
    __shared__ int gb[NB];
    __shared__ int s[1024];
    const int t = threadIdx.x;
    const int base = blockIdx.x * EPB;
    const int n = min(EPB, N_EDGES - base);

    if (t < NB) cnt[t] = 0;
    __syncthreads();
    for (int i = t; i < n; i += 1024)
        atomicAdd(&cnt[edst[base + i] >> 7], 1);
    __syncthreads();
    const int v = (t < NB) ? cnt[t] : 0;
    s[t] = v;
    __syncthreads();
    for (int off = 1; off < 1024; off <<= 1) {
        const int x = (t >= off) ? s[t - off] : 0;
        __syncthreads();
        s[t] += x;
        __syncthreads();
    }
    if (t < NB) {
        const int excl = s[t] - v;          // exclusive prefix
        cur[t] = excl;
        gb[t] = (v ? atomicAdd(&gcur[t], v) : 0) - excl;
    }
    __syncthreads();
    for (int i = t; i < n; i += 1024) {     // coalesced re-read (L2-hot)
        const int d = edst[base + i];
        const int bkt = d >> 7;
        const int pos = atomicAdd(&cur[bkt], 1);
        stage[pos] = ((d & 127) << 17) | esrc[base + i];
        bkt16[pos] = (ushort_t)bkt;
    }
    __syncthreads();
    for (int i = t; i < n; i += 1024) {     // coalesced segment writes
        const int bkt = bkt16[i];
        const int gp = gb[bkt] + i;
        if (gp < (bkt + 1) * CAP)           // overflow guard (never expected)
            slab[gp] = stage[i];
    }
}

// ---------- 8-lane all-reduce on the VALU pipe (DPP, no DS ops) ----------
template<int CTRL>
__device__ __forceinline__ float fadd_dpp(float x) {
    const int r = __builtin_amdgcn_update_dpp(0, __float_as_int(x), CTRL, 0xF, 0xF, true);
    return x + __int_as_float(r);
}
__device__ __forceinline__ float red8(float p) {
    p = fadd_dpp<0xB1>(p);    // quad_perm [1,0,3,2]  : xor 1
    p = fadd_dpp<0x4E>(p);    // quad_perm [2,3,0,1]  : xor 2
    p = fadd_dpp<0x141>(p);   // row_half_mirror      : xor within 8
    return p;
}

// cvt 8 bf16 (uint4) -> g[8] fp32, and dot vs h[8]
__device__ __forceinline__ float cvt_dot(const uint4 u, const float* __restrict__ h,
                                         float* __restrict__ g) {
    g[0] = __uint_as_float(u.x << 16); g[1] = __uint_as_float(u.x & 0xFFFF0000u);
    g[2] = __uint_as_float(u.y << 16); g[3] = __uint_as_float(u.y & 0xFFFF0000u);
    g[4] = __uint_as_float(u.z << 16); g[5] = __uint_as_float(u.z & 0xFFFF0000u);
    g[6] = __uint_as_float(u.w << 16); g[7] = __uint_as_float(u.w & 0xFFFF0000u);
    float p = 0.f;
#pragma unroll
    for (int k = 0; k < 8; ++k) p += g[k] * h[k];
    return p;
}

// ---------- K3: fused SDDMM + SpMM (round-0 structure + degree perm) ----------
// One 128-node bucket per block. Counting-sort by (local_dst, src>>14).
// ONLY change vs the 49.5us round-0 kernel: slots pick nodes through a
// degree-rank permutation so the 8 slots of a wave get near-equal trip
// counts (wave time ~mean(deg) instead of max-of-8(deg)), and rank r pairs
// with rank 127-r across the two halves to equalize per-thread totals.
// acc stays confined to each half and is written straight to global --
// no state held across edge loops (the r1/r2 spill trigger).
__global__ __launch_bounds__(512) void fused_spmm(const float4* __restrict__ feat4,
                                                  const uint4* __restrict__ featb4,
                                                  const int* __restrict__ slab,
                                                  const int* __restrict__ gcur,
                                                  float4* __restrict__ neigh4) {
    __shared__ int seA[CAP];                // 12 KB: raw packed (slab cache)
    __shared__ int seB[CAP];                // 12 KB: srcs sorted by (dst,rng)
    __shared__ int cnt[1024];
    __shared__ int cur[1024];
    __shared__ int rowoff[129];
    __shared__ int s[512];
    __shared__ int degs[128];
    __shared__ int perm[128];
    const int t = threadIdx.x;
    const int b = blockIdx.x;
    const int nbase = b << 7;
    const int nb_nodes = min(128, N_NODES - nbase);
    const int sbase = b * CAP;
    const int ne = min(gcur[b] - sbase, CAP);

    for (int i = t; i < ne; i += 512) seA[i] = slab[sbase + i];
    cnt[t] = 0; cnt[t + 512] = 0;
    __syncthreads();
    for (int i = t; i < ne; i += 512) {
        const int pk = seA[i];
        atomicAdd(&cnt[((pk >> 17) << 3) | ((pk & 0x1FFFF) >> RSH)], 1);
    }
    __syncthreads();
    const int v0 = cnt[2 * t], v1 = cnt[2 * t + 1];
    const int sum = v0 + v1;
    s[t] = sum;
    __syncthreads();
    for (int off = 1; off < 512; off <<= 1) {
        const int x = (t >= off) ? s[t - off] : 0;
        __syncthreads();
        s[t] += x;
        __syncthreads();
    }
    const int excl = s[t] - sum;
    cur[2 * t] = excl;
    cur[2 * t + 1] = excl + v0;
    __syncthreads();
    if (t < 128) rowoff[t] = cur[t << 3];
    if (t == 0) rowoff[128] = ne;
    __syncthreads();
    if (t < 128) degs[t] = rowoff[t + 1] - rowoff[t];
    for (int i = t; i < ne; i += 512) {
        const int pk = seA[i];
        const int key = ((pk >> 17) << 3) | ((pk & 0x1FFFF) >> RSH);
        const int pos = atomicAdd(&cur[key], 1);
        seB[pos] = pk & 0x1FFFF;
    }
    __syncthreads();                        // degs + scatter complete
    // rank-sort nodes by degree: perm[rank] = node (O(128^2), LDS-broadcast)
    if (t < 128) {
        const int d = degs[t];
        int pos = 0;
        for (int j = 0; j < 128; ++j) {
            const int dj = degs[j];
            pos += (dj < d) || (dj == d && j < t);
        }
        perm[pos] = t;
    }
    __syncthreads();

    const int slot = t >> 3;                // 64 node-slots per block
    const int l = t & 7;                    // lane owns dims 8l..8l+7
#pragma unroll
    for (int half = 0; half < 2; ++half) {
        const int ln = half ? perm[127 - slot] : perm[slot];
        if (ln >= nb_nodes) continue;       // no barriers below: safe
        const int nidx = nbase + ln;
        float h[8];
        {
            const float4 ha = feat4[nidx * 16 + 2 * l];
            const float4 hb = feat4[nidx * 16 + 2 * l + 1];
            h[0] = ha.x; h[1] = ha.y; h[2] = ha.z; h[3] = ha.w;
            h[4] = hb.x; h[5] = hb.y; h[6] = hb.z; h[7] = hb.w;
        }
        float acc[8];
#pragma unroll
        for (int k = 0; k < 8; ++k) acc[k] = 0.f;

        int e = rowoff[ln];
        const int e1 = rowoff[ln + 1];
        for (; e + 3 < e1; e += 4) {
            const int s0 = seB[e], s1 = seB[e + 1], s2 = seB[e + 2], s3 = seB[e + 3];
            const uint4 u0 = featb4[s0 * 8 + l];   // 4 gathers in flight
            const uint4 u1 = featb4[s1 * 8 + l];
            const uint4 u2 = featb4[s2 * 8 + l];
            const uint4 u3 = featb4[s3 * 8 + l];
            float g0[8], g1[8], g2[8], g3[8];
            float p0 = cvt_dot(u0, h, g0);
            float p1 = cvt_dot(u1, h, g1);
            float p2 = cvt_dot(u2, h, g2);
            float p3 = cvt_dot(u3, h, g3);
            p0 = red8(p0); p1 = red8(p1); p2 = red8(p2); p3 = red8(p3);
#pragma unroll
            for (int k = 0; k < 8; ++k)
                acc[k] += g0[k] * p0 + g1[k] * p1 + g2[k] * p2 + g3[k] * p3;
        }
        for (; e < e1; ++e) {
            const uint4 u0 = featb4[seB[e] * 8 + l];
            float g0[8];
            float p0 = red8(cvt_dot(u0, h, g0));
#pragma unroll
            for (int k = 0; k < 8; ++k) acc[k] += g0[k] * p0;
        }
        neigh4[nidx * 16 + 2 * l]     = make_float4(acc[0], acc[1], acc[2], acc[3]);
        neigh4[nidx * 16 + 2 * l + 1] = make_float4(acc[4], acc[5], acc[6], acc[7]);
    }
}

// ---------- K4: in-place GEMM out[n,:] = out[n,:] @ W^T ----------
__global__ __launch_bounds__(256) void gemm_inplace(float* __restrict__ out,
                                                    const float* __restrict__ W) {
    __shared__ float WT[64][68];
    __shared__ float nT[64][132];
    const int t = threadIdx.x;

    const float4* W4 = (const float4*)W;
#pragma unroll
    for (int j = 0; j < 4; ++j) {
        const int f = t + j * 256;
        const int o = f >> 4;
        const int i4 = (f & 15) * 4;
        const float4 w = W4[f];
        WT[i4 + 0][o] = w.x;
        WT[i4 + 1][o] = w.y;
        WT[i4 + 2][o] = w.z;
        WT[i4 + 3][o] = w.w;
    }

    const int base = blockIdx.x * 128;
    const int rows = min(128, N_NODES - base);
    const float4* O4 = (const float4*)(out + (long)base * D);
#pragma unroll
    for (int j = 0; j < 8; ++j) {
        const int f = t + j * 256;
        const int r = f >> 4;
        const int i4 = (f & 15) * 4;
        if (r < rows) {
            const float4 x = O4[f];
            nT[i4 + 0][r] = x.x;
            nT[i4 + 1][r] = x.y;
            nT[i4 + 2][r] = x.z;
            nT[i4 + 3][r] = x.w;
        }
    }
    __syncthreads();

    const int c4 = (t & 15) * 4;
    const int r0 = (t >> 4) * 8;
    float acc[8][4];
#pragma unroll
    for (int r = 0; r < 8; ++r)
#pragma unroll
        for (int c = 0; c < 4; ++c) acc[r][c] = 0.f;

    for (int i = 0; i < 64; ++i) {
        const float4 w = *(const float4*)&WT[i][c4];
        const float4 ra = *(const float4*)&nT[i][r0];
        const float4 rb = *(const float4*)&nT[i][r0 + 4];
        const float wv[4] = {w.x, w.y, w.z, w.w};
        const float rv[8] = {ra.x, ra.y, ra.z, ra.w, rb.x, rb.y, rb.z, rb.w};
#pragma unroll
        for (int r = 0; r < 8; ++r)
#pragma unroll
            for (int c = 0; c < 4; ++c) acc[r][c] += rv[r] * wv[c];
    }

#pragma unroll
    for (int r = 0; r < 8; ++r) {
        const int rr = r0 + r;
        if (rr < rows)
            *(float4*)&out[(long)(base + rr) * D + c4] =
                make_float4(acc[r][0], acc[r][1], acc[r][2], acc[r][3]);
    }
}

extern "C" void kernel_launch(void* const* d_in, const int* in_sizes, int n_in,
                              void* d_out, int out_size, void* d_ws, size_t ws_size,
                              hipStream_t stream) {
    const float* feat = (const float*)d_in[0];
    const int*   esrc = (const int*)d_in[1];
    const int*   edst = (const int*)d_in[2];
    const float* W    = (const float*)d_in[3];
    float* out = (float*)d_out;

    char* ws = (char*)d_ws;
    ushort_t* featb = (ushort_t*)(ws);                       // 12.8 MB
    int* slab = (int*)(ws + 12800000);                       // NB*CAP*4 = 9.61 MB
    int* gcur = (int*)(ws + 12800000 + (size_t)NB * CAP * 4);// 3.1 KB

    repack_init<<<(N_NODES * D / 16 + 255) / 256, 256, 0, stream>>>(feat, featb, gcur);
    partition<<<NPART, 1024, 0, stream>>>(esrc, edst, gcur, slab);
    fused_spmm<<<NB, 512, 0, stream>>>((const float4*)feat, (const uint4*)featb,
                                       slab, gcur, (float4*)out);
    gemm_inplace<<<(N_NODES + 127) / 128, 256, 0, stream>>>(out, W);
}